// Round 15
// baseline (2017.038 us; speedup 1.0000x reference)
//
#include <hip/hip_runtime.h>
#include <stdint.h>

#define NSEQ 512
#define XS 104   // cond stride (shorts): 96 + pad
#define HS 132   // raw-h stride (f32): 128 + pad
#define PS 36    // part stride (f32): 16 f2 slots + pad
#define ZS 76    // zbuf stride (shorts): 64 + pad (2-way banks)
#define EPS 1e-5f

typedef short bfrag __attribute__((ext_vector_type(8)));
typedef float f4 __attribute__((ext_vector_type(4)));
#define MFMA16 __builtin_amdgcn_mfma_f32_16x16x32_bf16

__device__ __forceinline__ unsigned short f2bf(float f){
  uint32_t u = __float_as_uint(f);
  u += 0x7FFFu + ((u>>16)&1u);   // RNE
  return (unsigned short)(u>>16);
}
__device__ __forceinline__ uint32_t pk2bf(float a, float b){
  uint32_t r;
  asm("v_cvt_pk_bf16_f32 %0, %1, %2" : "=v"(r) : "v"(a), "v"(b));
  return r;
}
__device__ __forceinline__ float tanh_fast(float v){
  float e = __builtin_amdgcn_exp2f(v * 2.8853900817779268f);  // e^(2v)
  float r = __builtin_amdgcn_rcpf(e + 1.f);
  return fmaf(-2.f, r, 1.f);
}
// LDS-only barrier: global loads/stores stay in flight across it
__device__ __forceinline__ void lds_barrier(){
  asm volatile("s_waitcnt lgkmcnt(0)" ::: "memory");
  __builtin_amdgcn_s_barrier();
  asm volatile("" ::: "memory");
}

// stats over lane's 8 neurons -> direct f2 write, 16 slots/row
__device__ __forceinline__ void stats_write(const float (&h0)[4], const float (&h1)[4],
                                            float* __restrict__ part,
                                            const int w, const int lg, const int lc){
  const float s = ((h0[0]+h0[1])+(h0[2]+h0[3])) + ((h1[0]+h1[1])+(h1[2]+h1[3]));
  const float q = (fmaf(h0[0],h0[0], h0[1]*h0[1]) + fmaf(h0[2],h0[2], h0[3]*h0[3]))
                + (fmaf(h1[0],h1[0], h1[1]*h1[1]) + fmaf(h1[2],h1[2], h1[3]*h1[3]));
  *(float2*)(part + lc*PS + (w*4+lg)*2) = make_float2(s, q);
}

__device__ __forceinline__ void ln_mu_rs(const float* __restrict__ part, const int lc,
                                         float& mu, float& rs){
  const float* pr = part + lc*PS;
  const f4 p0=*(const f4*)(pr),    p1=*(const f4*)(pr+4),  p2=*(const f4*)(pr+8),  p3=*(const f4*)(pr+12);
  const f4 p4=*(const f4*)(pr+16), p5=*(const f4*)(pr+20), p6=*(const f4*)(pr+24), p7=*(const f4*)(pr+28);
  const float ss = (((p0.x+p0.z)+(p1.x+p1.z)) + ((p2.x+p2.z)+(p3.x+p3.z)))
                 + (((p4.x+p4.z)+(p5.x+p5.z)) + ((p6.x+p6.z)+(p7.x+p7.z)));
  const float qq = (((p0.y+p0.w)+(p1.y+p1.w)) + ((p2.y+p2.w)+(p3.y+p3.w)))
                 + (((p4.y+p4.w)+(p5.y+p5.w)) + ((p6.y+p6.w)+(p7.y+p7.w)));
  mu = ss * 0.0078125f;
  rs = rsqrtf(fmaf(qq, 0.0078125f, -mu*mu) + EPS);
}

// consumer-side LN: raw h (f32 LDS) + stats partials + packed (be,g) -> 4 B-frags
__device__ __forceinline__ void consume_ln(const float* __restrict__ hb,
    const float* __restrict__ part, const uint32_t* __restrict__ pg,
    bfrag (&B)[4], const int lg, const int lc){
  float mu, rs;
  ln_mu_rs(part, lc, mu, rs);
#pragma unroll
  for (int kt=0; kt<4; ++kt){
    const float* hp = hb + lc*HS + kt*32 + lg*8;
    const f4 ha = *(const f4*)(hp);
    const f4 hc = *(const f4*)(hp + 4);
    const uint4 q0 = *(const uint4*)(pg + kt*32 + lg*8);
    const uint4 q1 = *(const uint4*)(pg + kt*32 + lg*8 + 4);
    const uint32_t gu[8] = {q0.x,q0.y,q0.z,q0.w,q1.x,q1.y,q1.z,q1.w};
    float e[8];
#pragma unroll
    for (int j=0;j<8;++j){
      const float h = (j<4)? ha[j] : hc[j-4];
      const float gg = __uint_as_float(gu[j] & 0xFFFF0000u);
      const float bb = __uint_as_float(gu[j] << 16);
      e[j] = tanh_fast(fmaf((h - mu)*rs, gg, bb));
    }
    union { bfrag v; uint32_t u[4]; } r;
    r.u[0]=pk2bf(e[0],e[1]); r.u[1]=pk2bf(e[2],e[3]);
    r.u[2]=pk2bf(e[4],e[5]); r.u[3]=pk2bf(e[6],e[7]);
    B[kt]=r.v;
  }
}

__global__ __launch_bounds__(256, 1)
void latent_ode_v15(const float* __restrict__ z0, const float* __restrict__ tt,
                    const float* __restrict__ cond,
                    const float* __restrict__ W0, const float* __restrict__ b0,
                    const float* __restrict__ g0, const float* __restrict__ be0,
                    const float* __restrict__ W1, const float* __restrict__ b1,
                    const float* __restrict__ g1, const float* __restrict__ be1,
                    const float* __restrict__ W2, const float* __restrict__ b2,
                    const float* __restrict__ g2, const float* __restrict__ be2,
                    const float* __restrict__ Wo, const float* __restrict__ bo,
                    float* __restrict__ out)
{
  __shared__ __align__(16) unsigned short xin[16*XS];    // cond bf16
  __shared__ __align__(16) unsigned short zbuf[16*ZS];   // z bf16
  __shared__ __align__(16) float hA[16*HS], hB[16*HS];   // raw h f32 (ping-pong)
  __shared__ __align__(16) float partA[16*PS], partB[16*PS];
  __shared__ __align__(16) uint32_t pgb[3*128];          // packed (be,g) per layer

  const int t  = threadIdx.x;     // 0..255, 4 waves
  const int w  = t >> 6;
  const int l  = t & 63;
  const int lg = l >> 4;
  const int lc = l & 15;
  const int r0 = blockIdx.x * 16;
  const int zcol = w*16 + lg*4;

  // ---- weight fragments (v9 verbatim: lane owns 8 contiguous neurons)
  bfrag A0z[2][2], A0c[2][3], A1f[2][4], A2f[2][4], Aof[4];
#pragma unroll
  for (int nt=0; nt<2; ++nt){
    const int col = w*32 + nt*4 + ((lc>>2)<<3) + (lc&3);
#pragma unroll
    for (int kt=0; kt<2; ++kt){
      union { bfrag v; unsigned short u[8]; } r;
#pragma unroll
      for (int j=0; j<8; ++j) r.u[j] = f2bf(W0[(size_t)(kt*32 + lg*8 + j)*128 + col]);
      A0z[nt][kt] = r.v;
    }
#pragma unroll
    for (int s=0; s<3; ++s){
      union { bfrag v; unsigned short u[8]; } r;
#pragma unroll
      for (int j=0; j<8; ++j) r.u[j] = f2bf(W0[(size_t)(64 + s*32 + lg*8 + j)*128 + col]);
      A0c[nt][s] = r.v;
    }
#pragma unroll
    for (int kt=0; kt<4; ++kt){
      union { bfrag v; unsigned short u[8]; } r1, r2;
#pragma unroll
      for (int j=0; j<8; ++j){
        const int k = kt*32 + lg*8 + j;
        r1.u[j] = f2bf(W1[(size_t)k*128 + col]);
        r2.u[j] = f2bf(W2[(size_t)k*128 + col]);
      }
      A1f[nt][kt] = r1.v; A2f[nt][kt] = r2.v;
    }
  }
#pragma unroll
  for (int kt=0; kt<4; ++kt){
    union { bfrag v; unsigned short u[8]; } r;
#pragma unroll
    for (int j=0; j<8; ++j)
      r.u[j] = f2bf(Wo[(size_t)(kt*32 + lg*8 + j)*64 + (w*16 + lc)]);
    Aof[kt] = r.v;
  }
  // producer-side biases only (LN params live packed in LDS)
  float bd0[2][4], bd1[2][4], bd2[2][4], bo_d[4];
#pragma unroll
  for (int nt=0; nt<2; ++nt){
#pragma unroll
    for (int g=0; g<4; ++g){
      const int n = w*32 + lg*8 + nt*4 + g;
      bd0[nt][g]=b0[n]; bd1[nt][g]=b1[n]; bd2[nt][g]=b2[n];
    }
  }
#pragma unroll
  for (int g=0; g<4; ++g) bo_d[g] = bo[zcol + g];

  // ---- stage packed LN params (be low, g high)
  for (int idx=t; idx<384; idx+=256){
    const int n = idx & 127;
    float gv, bv;
    if (idx < 128){ gv = g0[n]; bv = be0[n]; }
    else if (idx < 256){ gv = g1[n]; bv = be1[n]; }
    else { gv = g2[n]; bv = be2[n]; }
    pgb[idx] = pk2bf(bv, gv);
  }

  // ---- t pipeline
  const float* tp = tt + (size_t)(r0+lc)*NSEQ;
  float tcv = tp[0], tnv = tp[1];

  // ---- z init
  f4 zr;
  {
    const f4 zv = *(const f4*)(z0 + (size_t)(r0+lc)*64 + zcol);
    zr = zv;
    *(uint2*)(zbuf + lc*ZS + zcol) = make_uint2(pk2bf(zv[0],zv[1]), pk2bf(zv[2],zv[3]));
    *(f4*)(out + ((size_t)(r0+lc)*NSEQ)*64 + zcol) = zv;
  }

  // ---- cond staging: 12 threads/row x 8 f32 -> one b128 bf16 write (v9 verbatim)
  const bool stgW = (t < 192);
  const int srow = t / 12, s8 = t - srow*12;
  const float* cptr = cond + ((size_t)(r0+srow)*NSEQ)*96 + s8*8;
  float4 pf0 = {0,0,0,0}, pf1 = {0,0,0,0};
  if (stgW){
    const float4 c0 = *(const float4*)(cptr);
    const float4 c1 = *(const float4*)(cptr + 4);
    uint4 u;
    u.x = pk2bf(c0.x,c0.y); u.y = pk2bf(c0.z,c0.w);
    u.z = pk2bf(c1.x,c1.y); u.w = pk2bf(c1.z,c1.w);
    *(uint4*)(xin + srow*XS + s8*8) = u;
    pf0 = *(const float4*)(cptr + 96);
    pf1 = *(const float4*)(cptr + 100);
  }
  lds_barrier();

  // ---- prologue preacc of cond(0)
  f4 apC[2];
  {
    const int o = lc*XS + lg*8;
    const bfrag c0 = *(const bfrag*)(xin + o);
    const bfrag c1 = *(const bfrag*)(xin + o + 32);
    const bfrag c2 = *(const bfrag*)(xin + o + 64);
    const f4 z4 = {0,0,0,0};
#pragma unroll
    for (int nt=0; nt<2; ++nt){
      f4 a = MFMA16(A0c[nt][0], c0, z4, 0,0,0);
      a = MFMA16(A0c[nt][1], c1, a, 0,0,0);
      a = MFMA16(A0c[nt][2], c2, a, 0,0,0);
      apC[nt] = a;
    }
  }
  lds_barrier();   // protect cond(0) reads from step-0 staging overwrite

  float h0[4], h1[4];
  for (int i=0; i<NSEQ-1; ++i){
    // ---- S1: L0 z-part + combine preacc; raw-h + stats; stage cond(i+1); t prefetch
    const int ip2 = (i+2 <= NSEQ-1) ? (i+2) : (NSEQ-1);
    const float tfv = tp[ip2];
    {
      const int o = lc*ZS + lg*8;
      const bfrag bz0 = *(const bfrag*)(zbuf + o);
      const bfrag bz1 = *(const bfrag*)(zbuf + o + 32);
      const f4 z4 = {0,0,0,0};
      f4 c0 = MFMA16(A0z[0][0], bz0, z4, 0,0,0);
      f4 c1 = MFMA16(A0z[1][0], bz0, z4, 0,0,0);
      c0 = MFMA16(A0z[0][1], bz1, c0, 0,0,0);
      c1 = MFMA16(A0z[1][1], bz1, c1, 0,0,0);
      f4 vh0, vh1;
#pragma unroll
      for (int g=0; g<4; ++g){
        h0[g] = (c0[g] + apC[0][g]) + bd0[0][g];
        h1[g] = (c1[g] + apC[1][g]) + bd0[1][g];
        vh0[g] = h0[g]; vh1[g] = h1[g];
      }
      stats_write(h0, h1, partA, w, lg, lc);
      float* hw = hA + lc*HS + w*32 + lg*8;
      *(f4*)(hw) = vh0;
      *(f4*)(hw + 4) = vh1;
    }
    if (stgW){
      uint4 u;
      u.x = pk2bf(pf0.x,pf0.y); u.y = pk2bf(pf0.z,pf0.w);
      u.z = pk2bf(pf1.x,pf1.y); u.w = pk2bf(pf1.z,pf1.w);
      *(uint4*)(xin + srow*XS + s8*8) = u;
      if (i < NSEQ-2){
        pf0 = *(const float4*)(cptr + (size_t)(i+2)*96);
        pf1 = *(const float4*)(cptr + (size_t)(i+2)*96 + 4);
      }
    }
    lds_barrier();   // B1

    // ---- S2: consume LN0 + L1 + raw-h/stats; preacc cond(i+1)
    {
      const int o = lc*XS + lg*8;
      const bfrag c0 = *(const bfrag*)(xin + o);
      const bfrag c1 = *(const bfrag*)(xin + o + 32);
      const bfrag c2 = *(const bfrag*)(xin + o + 64);
      const f4 z4 = {0,0,0,0};
      f4 a0 = MFMA16(A0c[0][0], c0, z4, 0,0,0);
      f4 a1 = MFMA16(A0c[1][0], c0, z4, 0,0,0);
      a0 = MFMA16(A0c[0][1], c1, a0, 0,0,0);
      a1 = MFMA16(A0c[1][1], c1, a1, 0,0,0);
      a0 = MFMA16(A0c[0][2], c2, a0, 0,0,0);
      a1 = MFMA16(A0c[1][2], c2, a1, 0,0,0);

      bfrag B[4];
      consume_ln(hA, partA, pgb, B, lg, lc);
      f4 ca0 = MFMA16(A1f[0][0], B[0], z4, 0,0,0);
      f4 cb0 = MFMA16(A1f[0][1], B[1], z4, 0,0,0);
      f4 ca1 = MFMA16(A1f[1][0], B[0], z4, 0,0,0);
      f4 cb1 = MFMA16(A1f[1][1], B[1], z4, 0,0,0);
      ca0 = MFMA16(A1f[0][2], B[2], ca0, 0,0,0);
      cb0 = MFMA16(A1f[0][3], B[3], cb0, 0,0,0);
      ca1 = MFMA16(A1f[1][2], B[2], ca1, 0,0,0);
      cb1 = MFMA16(A1f[1][3], B[3], cb1, 0,0,0);
      f4 vh0, vh1;
#pragma unroll
      for (int g=0; g<4; ++g){
        h0[g] = (ca0[g]+cb0[g]) + bd1[0][g];
        h1[g] = (ca1[g]+cb1[g]) + bd1[1][g];
        vh0[g] = h0[g]; vh1[g] = h1[g];
      }
      stats_write(h0, h1, partB, w, lg, lc);
      float* hw = hB + lc*HS + w*32 + lg*8;
      *(f4*)(hw) = vh0;
      *(f4*)(hw + 4) = vh1;
      apC[0] = a0; apC[1] = a1;
    }
    lds_barrier();   // B2

    // ---- S3: consume LN1 + L2 + raw-h/stats
    {
      const f4 z4 = {0,0,0,0};
      bfrag B[4];
      consume_ln(hB, partB, pgb + 128, B, lg, lc);
      f4 ca0 = MFMA16(A2f[0][0], B[0], z4, 0,0,0);
      f4 cb0 = MFMA16(A2f[0][1], B[1], z4, 0,0,0);
      f4 ca1 = MFMA16(A2f[1][0], B[0], z4, 0,0,0);
      f4 cb1 = MFMA16(A2f[1][1], B[1], z4, 0,0,0);
      ca0 = MFMA16(A2f[0][2], B[2], ca0, 0,0,0);
      cb0 = MFMA16(A2f[0][3], B[3], cb0, 0,0,0);
      ca1 = MFMA16(A2f[1][2], B[2], ca1, 0,0,0);
      cb1 = MFMA16(A2f[1][3], B[3], cb1, 0,0,0);
      f4 vh0, vh1;
#pragma unroll
      for (int g=0; g<4; ++g){
        h0[g] = (ca0[g]+cb0[g]) + bd2[0][g];
        h1[g] = (ca1[g]+cb1[g]) + bd2[1][g];
        vh0[g] = h0[g]; vh1[g] = h1[g];
      }
      stats_write(h0, h1, partA, w, lg, lc);
      float* hw = hA + lc*HS + w*32 + lg*8;
      *(f4*)(hw) = vh0;
      *(f4*)(hw + 4) = vh1;
    }
    lds_barrier();   // B3

    // ---- S4: consume LN2 + Lo + Euler + stores
    {
      const f4 z4 = {0,0,0,0};
      bfrag B[4];
      consume_ln(hA, partA, pgb + 256, B, lg, lc);
      f4 aa = MFMA16(Aof[0], B[0], z4, 0,0,0);
      f4 ab = MFMA16(Aof[1], B[1], z4, 0,0,0);
      aa = MFMA16(Aof[2], B[2], aa, 0,0,0);
      ab = MFMA16(Aof[3], B[3], ab, 0,0,0);
      const float dt = tnv - tcv;
      f4 zn;
#pragma unroll
      for (int g=0; g<4; ++g) zn[g] = fmaf(dt, (aa[g]+ab[g]) + bo_d[g], zr[g]);
      zr = zn;
      *(uint2*)(zbuf + lc*ZS + zcol) = make_uint2(pk2bf(zn[0],zn[1]), pk2bf(zn[2],zn[3]));
      *(f4*)(out + ((size_t)(r0+lc)*NSEQ + (size_t)(i+1))*64 + zcol) = zn;
      tcv = tnv; tnv = tfv;
    }
    lds_barrier();   // B4
  }
}

extern "C" void kernel_launch(void* const* d_in, const int* in_sizes, int n_in,
                              void* d_out, int out_size, void* d_ws, size_t ws_size,
                              hipStream_t stream) {
  const float* z0   = (const float*)d_in[0];
  const float* tt   = (const float*)d_in[1];
  const float* cond = (const float*)d_in[2];
  const float* W0   = (const float*)d_in[3];
  const float* b0   = (const float*)d_in[4];
  const float* g0   = (const float*)d_in[5];
  const float* be0  = (const float*)d_in[6];
  const float* W1   = (const float*)d_in[7];
  const float* b1   = (const float*)d_in[8];
  const float* g1   = (const float*)d_in[9];
  const float* be1  = (const float*)d_in[10];
  const float* W2   = (const float*)d_in[11];
  const float* b2   = (const float*)d_in[12];
  const float* g2   = (const float*)d_in[13];
  const float* be2  = (const float*)d_in[14];
  const float* Wo   = (const float*)d_in[15];
  const float* bo   = (const float*)d_in[16];
  float* out = (float*)d_out;

  hipLaunchKernelGGL(latent_ode_v15, dim3(64), dim3(256), 0, stream,
                     z0, tt, cond, W0, b0, g0, be0, W1, b1, g1, be1,
                     W2, b2, g2, be2, Wo, bo, out);
}

// Round 16
// 1110.911 us; speedup vs baseline: 1.8157x; 1.8157x over previous
//
#include <hip/hip_runtime.h>
#include <stdint.h>

#define NSEQ 512
#define XS 168   // xin row stride (shorts): [0:64 z][64:160 cond] + pad
#define AS 136   // act row stride (shorts)
#define PS 36    // part row stride (f32): 16 float2 slots + pad
#define EPS 1e-5f

typedef short bfrag __attribute__((ext_vector_type(8)));
typedef float f4 __attribute__((ext_vector_type(4)));
#define MFMA16 __builtin_amdgcn_mfma_f32_16x16x32_bf16

__device__ __forceinline__ unsigned short f2bf(float f){
  uint32_t u = __float_as_uint(f);
  u += 0x7FFFu + ((u>>16)&1u);   // RNE
  return (unsigned short)(u>>16);
}
__device__ __forceinline__ uint32_t pk2bf(float a, float b){
  uint32_t r;
  asm("v_cvt_pk_bf16_f32 %0, %1, %2" : "=v"(r) : "v"(a), "v"(b));
  return r;
}
__device__ __forceinline__ float tanh_fast(float v){
  float e = __builtin_amdgcn_exp2f(v * 2.8853900817779268f);  // e^(2v)
  float r = __builtin_amdgcn_rcpf(e + 1.f);
  return fmaf(-2.f, r, 1.f);
}
// LDS-only barrier: global loads/stores stay in flight across it
__device__ __forceinline__ void lds_barrier(){
  asm volatile("s_waitcnt lgkmcnt(0)" ::: "memory");
  __builtin_amdgcn_s_barrier();
  asm volatile("" ::: "memory");
}

// stats over lane's 8 neurons -> direct f2 write, 16 slots/row (no shuffles)
__device__ __forceinline__ void stats_write(const float (&h0)[4], const float (&h1)[4],
                                            float* __restrict__ part,
                                            const int w, const int lg, const int lc){
  const float s = ((h0[0]+h0[1])+(h0[2]+h0[3])) + ((h1[0]+h1[1])+(h1[2]+h1[3]));
  const float q = (fmaf(h0[0],h0[0], h0[1]*h0[1]) + fmaf(h0[2],h0[2], h0[3]*h0[3]))
                + (fmaf(h1[0],h1[0], h1[1]*h1[1]) + fmaf(h1[2],h1[2], h1[3]*h1[3]));
  *(float2*)(part + lc*PS + (w*4+lg)*2) = make_float2(s, q);
}

// LN + tanh + single-b128 act store (lane's 8 contiguous neurons w*32+lg*8+0..7)
__device__ __forceinline__ void ln_tanh_store(const float (&h0)[4], const float (&h1)[4],
    const float (&gd)[2][4], const float (&bed)[2][4],
    const float* __restrict__ part, unsigned short* __restrict__ actb,
    const int w, const int lg, const int lc){
  const float* pr = part + lc*PS;
  const f4 p0=*(const f4*)(pr),    p1=*(const f4*)(pr+4),  p2=*(const f4*)(pr+8),  p3=*(const f4*)(pr+12);
  const f4 p4=*(const f4*)(pr+16), p5=*(const f4*)(pr+20), p6=*(const f4*)(pr+24), p7=*(const f4*)(pr+28);
  const float ss = (((p0.x+p0.z)+(p1.x+p1.z)) + ((p2.x+p2.z)+(p3.x+p3.z)))
                 + (((p4.x+p4.z)+(p5.x+p5.z)) + ((p6.x+p6.z)+(p7.x+p7.z)));
  const float qq = (((p0.y+p0.w)+(p1.y+p1.w)) + ((p2.y+p2.w)+(p3.y+p3.w)))
                 + (((p4.y+p4.w)+(p5.y+p5.w)) + ((p6.y+p6.w)+(p7.y+p7.w)));
  const float mu = ss * 0.0078125f;
  const float rs = rsqrtf(fmaf(qq, 0.0078125f, -mu*mu) + EPS);
  float e0[4], e1[4];
#pragma unroll
  for (int g=0; g<4; ++g){
    e0[g] = tanh_fast(fmaf((h0[g]-mu)*rs, gd[0][g], bed[0][g]));
    e1[g] = tanh_fast(fmaf((h1[g]-mu)*rs, gd[1][g], bed[1][g]));
  }
  uint4 pk4;
  pk4.x = pk2bf(e0[0],e0[1]); pk4.y = pk2bf(e0[2],e0[3]);
  pk4.z = pk2bf(e1[0],e1[1]); pk4.w = pk2bf(e1[2],e1[3]);
  *(uint4*)(actb + lc*AS + w*32 + lg*8) = pk4;
}

__global__ __launch_bounds__(256, 1)
void latent_ode_v9(const float* __restrict__ z0, const float* __restrict__ tt,
                   const float* __restrict__ cond,
                   const float* __restrict__ W0, const float* __restrict__ b0,
                   const float* __restrict__ g0, const float* __restrict__ be0,
                   const float* __restrict__ W1, const float* __restrict__ b1,
                   const float* __restrict__ g1, const float* __restrict__ be1,
                   const float* __restrict__ W2, const float* __restrict__ b2,
                   const float* __restrict__ g2, const float* __restrict__ be2,
                   const float* __restrict__ Wo, const float* __restrict__ bo,
                   float* __restrict__ out)
{
  __shared__ __align__(16) unsigned short xin[16*XS];
  __shared__ __align__(16) unsigned short act[16*AS];
  __shared__ __align__(16) float part[16*PS];

  const int t  = threadIdx.x;     // 0..255, 4 waves
  const int w  = t >> 6;
  const int l  = t & 63;
  const int lg = l >> 4;
  const int lc = l & 15;
  const int r0 = blockIdx.x * 16;
  const int zcol = w*16 + lg*4;

  // ---- weight fragments (row permutation -> lane owns 8 contiguous neurons)
  bfrag A0z[2][2], A0c[2][3], A1f[2][4], A2f[2][4], Aof[4];
#pragma unroll
  for (int nt=0; nt<2; ++nt){
    const int col = w*32 + nt*4 + ((lc>>2)<<3) + (lc&3);
#pragma unroll
    for (int kt=0; kt<2; ++kt){
      union { bfrag v; unsigned short u[8]; } r;
#pragma unroll
      for (int j=0; j<8; ++j) r.u[j] = f2bf(W0[(size_t)(kt*32 + lg*8 + j)*128 + col]);
      A0z[nt][kt] = r.v;
    }
#pragma unroll
    for (int s=0; s<3; ++s){
      union { bfrag v; unsigned short u[8]; } r;
#pragma unroll
      for (int j=0; j<8; ++j) r.u[j] = f2bf(W0[(size_t)(64 + s*32 + lg*8 + j)*128 + col]);
      A0c[nt][s] = r.v;
    }
#pragma unroll
    for (int kt=0; kt<4; ++kt){
      union { bfrag v; unsigned short u[8]; } r1, r2;
#pragma unroll
      for (int j=0; j<8; ++j){
        const int k = kt*32 + lg*8 + j;
        r1.u[j] = f2bf(W1[(size_t)k*128 + col]);
        r2.u[j] = f2bf(W2[(size_t)k*128 + col]);
      }
      A1f[nt][kt] = r1.v; A2f[nt][kt] = r2.v;
    }
  }
#pragma unroll
  for (int kt=0; kt<4; ++kt){
    union { bfrag v; unsigned short u[8]; } r;
#pragma unroll
    for (int j=0; j<8; ++j)
      r.u[j] = f2bf(Wo[(size_t)(kt*32 + lg*8 + j)*64 + (w*16 + lc)]);
    Aof[kt] = r.v;
  }
  float bd0[2][4], gd0[2][4], bed0[2][4];
  float bd1[2][4], gd1[2][4], bed1[2][4];
  float bd2[2][4], gd2[2][4], bed2[2][4];
  float bo_d[4];
#pragma unroll
  for (int nt=0; nt<2; ++nt){
#pragma unroll
    for (int g=0; g<4; ++g){
      const int n = w*32 + lg*8 + nt*4 + g;
      bd0[nt][g]=b0[n]; gd0[nt][g]=g0[n]; bed0[nt][g]=be0[n];
      bd1[nt][g]=b1[n]; gd1[nt][g]=g1[n]; bed1[nt][g]=be1[n];
      bd2[nt][g]=b2[n]; gd2[nt][g]=g2[n]; bed2[nt][g]=be2[n];
    }
  }
#pragma unroll
  for (int g=0; g<4; ++g) bo_d[g] = bo[zcol + g];

  // ---- t pipeline (registers, one prefetch per step)
  const float* tp = tt + (size_t)(r0+lc)*NSEQ;
  float tcv = tp[0], tnv = tp[1];

  // ---- z init
  f4 zr;
  {
    const f4 zv = *(const f4*)(z0 + (size_t)(r0+lc)*64 + zcol);
    zr = zv;
    *(f4*)(out + ((size_t)(r0+lc)*NSEQ)*64 + zcol) = zv;
    *(uint2*)(xin + lc*XS + zcol) = make_uint2(pk2bf(zv[0],zv[1]), pk2bf(zv[2],zv[3]));
  }

  // ---- cond staging: 12 threads/row x 8 f32 -> one b128 bf16 write
  const bool stgW = (t < 192);
  const int srow = t / 12, s8 = t - srow*12;
  const float* cptr = cond + ((size_t)(r0+srow)*NSEQ)*96 + s8*8;
  float4 pf0 = {0,0,0,0}, pf1 = {0,0,0,0};
  if (stgW){
    const float4 c0 = *(const float4*)(cptr);
    const float4 c1 = *(const float4*)(cptr + 4);
    uint4 u;
    u.x = pk2bf(c0.x,c0.y); u.y = pk2bf(c0.z,c0.w);
    u.z = pk2bf(c1.x,c1.y); u.w = pk2bf(c1.z,c1.w);
    *(uint4*)(xin + srow*XS + 64 + s8*8) = u;
    pf0 = *(const float4*)(cptr + 96);
    pf1 = *(const float4*)(cptr + 100);
  }
  lds_barrier();

  // ---- prologue preacc of cond(0)
  f4 apC[2];
  {
    const int o = lc*XS + 64 + lg*8;
    const bfrag c0 = *(const bfrag*)(xin + o);
    const bfrag c1 = *(const bfrag*)(xin + o + 32);
    const bfrag c2 = *(const bfrag*)(xin + o + 64);
    const f4 z4 = {0,0,0,0};
#pragma unroll
    for (int nt=0; nt<2; ++nt){
      f4 a = MFMA16(A0c[nt][0], c0, z4, 0,0,0);
      a = MFMA16(A0c[nt][1], c1, a, 0,0,0);
      a = MFMA16(A0c[nt][2], c2, a, 0,0,0);
      apC[nt] = a;
    }
  }
  lds_barrier();   // protect cond(0) reads from step-0 staging overwrite

  float h0[4], h1[4];
  for (int i=0; i<NSEQ-1; ++i){
    // ---- S_A: L0 z-part + combine preacc; stats; stage cond(i+1); t prefetch
    const int ip2 = (i+2 <= NSEQ-1) ? (i+2) : (NSEQ-1);
    const float tfv = tp[ip2];
    {
      const int o = lc*XS + lg*8;
      const bfrag bz0 = *(const bfrag*)(xin + o);
      const bfrag bz1 = *(const bfrag*)(xin + o + 32);
      const f4 z4 = {0,0,0,0};
      f4 c0 = MFMA16(A0z[0][0], bz0, z4, 0,0,0);
      f4 c1 = MFMA16(A0z[1][0], bz0, z4, 0,0,0);
      c0 = MFMA16(A0z[0][1], bz1, c0, 0,0,0);
      c1 = MFMA16(A0z[1][1], bz1, c1, 0,0,0);
#pragma unroll
      for (int g=0; g<4; ++g){
        h0[g] = (c0[g] + apC[0][g]) + bd0[0][g];
        h1[g] = (c1[g] + apC[1][g]) + bd0[1][g];
      }
      stats_write(h0, h1, part, w, lg, lc);
    }
    if (stgW){
      uint4 u;
      u.x = pk2bf(pf0.x,pf0.y); u.y = pk2bf(pf0.z,pf0.w);
      u.z = pk2bf(pf1.x,pf1.y); u.w = pk2bf(pf1.z,pf1.w);
      *(uint4*)(xin + srow*XS + 64 + s8*8) = u;
      if (i < NSEQ-2){
        pf0 = *(const float4*)(cptr + (size_t)(i+2)*96);
        pf1 = *(const float4*)(cptr + (size_t)(i+2)*96 + 4);
      }
    }
    lds_barrier();

    // ---- S_B: LN0 + preacc cond(i+1)
    {
      const int o = lc*XS + 64 + lg*8;
      const bfrag c0 = *(const bfrag*)(xin + o);
      const bfrag c1 = *(const bfrag*)(xin + o + 32);
      const bfrag c2 = *(const bfrag*)(xin + o + 64);
      const f4 z4 = {0,0,0,0};
      f4 a0 = MFMA16(A0c[0][0], c0, z4, 0,0,0);
      f4 a1 = MFMA16(A0c[1][0], c0, z4, 0,0,0);
      a0 = MFMA16(A0c[0][1], c1, a0, 0,0,0);
      a1 = MFMA16(A0c[1][1], c1, a1, 0,0,0);
      a0 = MFMA16(A0c[0][2], c2, a0, 0,0,0);
      a1 = MFMA16(A0c[1][2], c2, a1, 0,0,0);
      ln_tanh_store(h0, h1, gd0, bed0, part, act, w, lg, lc);
      apC[0] = a0; apC[1] = a1;
    }
    lds_barrier();

    // ---- S_C: L1
    {
      const int o = lc*AS + lg*8;
      const bfrag b0f = *(const bfrag*)(act + o);
      const bfrag b1f = *(const bfrag*)(act + o + 32);
      const bfrag b2f = *(const bfrag*)(act + o + 64);
      const bfrag b3f = *(const bfrag*)(act + o + 96);
      const f4 z4 = {0,0,0,0};
      f4 ca0 = MFMA16(A1f[0][0], b0f, z4, 0,0,0);
      f4 cb0 = MFMA16(A1f[0][1], b1f, z4, 0,0,0);
      f4 ca1 = MFMA16(A1f[1][0], b0f, z4, 0,0,0);
      f4 cb1 = MFMA16(A1f[1][1], b1f, z4, 0,0,0);
      ca0 = MFMA16(A1f[0][2], b2f, ca0, 0,0,0);
      cb0 = MFMA16(A1f[0][3], b3f, cb0, 0,0,0);
      ca1 = MFMA16(A1f[1][2], b2f, ca1, 0,0,0);
      cb1 = MFMA16(A1f[1][3], b3f, cb1, 0,0,0);
#pragma unroll
      for (int g=0; g<4; ++g){
        h0[g] = (ca0[g]+cb0[g]) + bd1[0][g];
        h1[g] = (ca1[g]+cb1[g]) + bd1[1][g];
      }
      stats_write(h0, h1, part, w, lg, lc);
    }
    lds_barrier();

    // ---- S_D: LN1
    ln_tanh_store(h0, h1, gd1, bed1, part, act, w, lg, lc);
    lds_barrier();

    // ---- S_E: L2
    {
      const int o = lc*AS + lg*8;
      const bfrag b0f = *(const bfrag*)(act + o);
      const bfrag b1f = *(const bfrag*)(act + o + 32);
      const bfrag b2f = *(const bfrag*)(act + o + 64);
      const bfrag b3f = *(const bfrag*)(act + o + 96);
      const f4 z4 = {0,0,0,0};
      f4 ca0 = MFMA16(A2f[0][0], b0f, z4, 0,0,0);
      f4 cb0 = MFMA16(A2f[0][1], b1f, z4, 0,0,0);
      f4 ca1 = MFMA16(A2f[1][0], b0f, z4, 0,0,0);
      f4 cb1 = MFMA16(A2f[1][1], b1f, z4, 0,0,0);
      ca0 = MFMA16(A2f[0][2], b2f, ca0, 0,0,0);
      cb0 = MFMA16(A2f[0][3], b3f, cb0, 0,0,0);
      ca1 = MFMA16(A2f[1][2], b2f, ca1, 0,0,0);
      cb1 = MFMA16(A2f[1][3], b3f, cb1, 0,0,0);
#pragma unroll
      for (int g=0; g<4; ++g){
        h0[g] = (ca0[g]+cb0[g]) + bd2[0][g];
        h1[g] = (ca1[g]+cb1[g]) + bd2[1][g];
      }
      stats_write(h0, h1, part, w, lg, lc);
    }
    lds_barrier();

    // ---- S_F: LN2
    ln_tanh_store(h0, h1, gd2, bed2, part, act, w, lg, lc);
    lds_barrier();

    // ---- S_G: Lo + Euler + stores
    {
      const int o = lc*AS + lg*8;
      const bfrag b0f = *(const bfrag*)(act + o);
      const bfrag b1f = *(const bfrag*)(act + o + 32);
      const bfrag b2f = *(const bfrag*)(act + o + 64);
      const bfrag b3f = *(const bfrag*)(act + o + 96);
      const f4 z4 = {0,0,0,0};
      f4 aa = MFMA16(Aof[0], b0f, z4, 0,0,0);
      f4 ab = MFMA16(Aof[1], b1f, z4, 0,0,0);
      aa = MFMA16(Aof[2], b2f, aa, 0,0,0);
      ab = MFMA16(Aof[3], b3f, ab, 0,0,0);
      const float dt = tnv - tcv;
      f4 zn;
#pragma unroll
      for (int g=0; g<4; ++g) zn[g] = fmaf(dt, (aa[g]+ab[g]) + bo_d[g], zr[g]);
      zr = zn;
      *(f4*)(out + ((size_t)(r0+lc)*NSEQ + (size_t)(i+1))*64 + zcol) = zn;
      *(uint2*)(xin + lc*XS + zcol) = make_uint2(pk2bf(zn[0],zn[1]), pk2bf(zn[2],zn[3]));
      tcv = tnv; tnv = tfv;
    }
    lds_barrier();
  }
}

extern "C" void kernel_launch(void* const* d_in, const int* in_sizes, int n_in,
                              void* d_out, int out_size, void* d_ws, size_t ws_size,
                              hipStream_t stream) {
  const float* z0   = (const float*)d_in[0];
  const float* tt   = (const float*)d_in[1];
  const float* cond = (const float*)d_in[2];
  const float* W0   = (const float*)d_in[3];
  const float* b0   = (const float*)d_in[4];
  const float* g0   = (const float*)d_in[5];
  const float* be0  = (const float*)d_in[6];
  const float* W1   = (const float*)d_in[7];
  const float* b1   = (const float*)d_in[8];
  const float* g1   = (const float*)d_in[9];
  const float* be1  = (const float*)d_in[10];
  const float* W2   = (const float*)d_in[11];
  const float* b2   = (const float*)d_in[12];
  const float* g2   = (const float*)d_in[13];
  const float* be2  = (const float*)d_in[14];
  const float* Wo   = (const float*)d_in[15];
  const float* bo   = (const float*)d_in[16];
  float* out = (float*)d_out;

  hipLaunchKernelGGL(latent_ode_v9, dim3(64), dim3(256), 0, stream,
                     z0, tt, cond, W0, b0, g0, be0, W1, b1, g1, be1,
                     W2, b2, g2, be2, Wo, bo, out);
}